// Round 7
// baseline (609.772 us; speedup 1.0000x reference)
//
#include <hip/hip_runtime.h>
#include <math.h>

// ============================================================================
// MoE FFN (dense, E=8): y = sum_e softmax(x@Wr)[:,e] * (gelu(x@W1_e+b1_e)@W2_e+b2_e)
// T=2048, D=1024, H=4096, E=8. FP32 in/out; bf16 MFMA compute.
// R10 -> R11: GEMM mainloop de-lockstepped: 2 barriers per K-tile (was 8).
// Audit: only the B(t+2)-stage into the live buffer needs a barrier (B-reads
// are register-consumed by the first two MM clusters); tile-end vmcnt(4)+BAR
// covers GLL landing. All sched_barrier(0) pins removed -> compiler's
// progressive lgkmcnt overlaps ds_reads under MFMA clusters (the 36%-
// MfmaUtil plateau across R3-R6 was phase-lockstep serializing LDS vs MFMA).
// vmcnt ledger unchanged (12 in flight -> wait 4). transconv split into two
// named kernels (trace diagnosis); body identical to R6.
// ws: PT | xb | WT | Hs. Tiers: A >=196.2MB, B >=28.2MB, D zero-ws fallback.
// ============================================================================

typedef float f32x4 __attribute__((ext_vector_type(4)));
typedef __bf16 bf16x8 __attribute__((ext_vector_type(8)));

#define GLL16(gp, lp)                                                          \
  __builtin_amdgcn_global_load_lds(                                            \
      (const __attribute__((address_space(1))) void*)(gp),                     \
      (__attribute__((address_space(3))) void*)(lp), 16, 0, 0)

// Branch-free GELU: erf via Abramowitz-Stegun 7.1.26 (|err| <= 1.5e-7).
__device__ __forceinline__ float gelu_f(float h) {
  float x = h * 0.70710678118654752f;
  float ax = fabsf(x);
  float t = __builtin_amdgcn_rcpf(fmaf(0.3275911f, ax, 1.0f));
  float p = fmaf(1.061405429f, t, -1.453152027f);
  p = fmaf(p, t, 1.421413741f);
  p = fmaf(p, t, -0.284496736f);
  p = fmaf(p, t, 0.254829592f);
  float e = __expf(-x * x);
  float erfv = fmaf(-p * t, e, 1.0f);
  erfv = copysignf(erfv, x);
  return 0.5f * h * (1.0f + erfv);
}

// ---------------------------------------------------------------------------
// pre_kernel: per row t -- router softmax (PT + probs_out), x -> bf16 (xb),
// y bias-init y[t] = sum_e P[t,e]*b2[e].  grid 512 x 256.
// ---------------------------------------------------------------------------
__global__ void pre_kernel(const float* __restrict__ x,
                           const float* __restrict__ rw,
                           const float* __restrict__ rb,
                           const float* __restrict__ b2,
                           float* __restrict__ PT,        // [8][2048]
                           float* __restrict__ probs_out,
                           __bf16* __restrict__ xb,
                           float* __restrict__ y)
{
  __shared__ float ps[4][8];
  const int tid = threadIdx.x;
  const int g = tid >> 6, l = tid & 63;
  const int t = blockIdx.x * 4 + g;
  const int d0 = l * 16;
  const float* xr = x + (size_t)t * 1024 + d0;

  f32x4 xv[4];
#pragma unroll
  for (int i = 0; i < 4; ++i) xv[i] = *(const f32x4*)(xr + i * 4);

  {
    bf16x8 o0, o1;
#pragma unroll
    for (int j = 0; j < 8; ++j) {
      o0[j] = (__bf16)xv[j >> 2][j & 3];
      o1[j] = (__bf16)xv[2 + (j >> 2)][j & 3];
    }
    *(bf16x8*)(xb + (size_t)t * 1024 + d0) = o0;
    *(bf16x8*)(xb + (size_t)t * 1024 + d0 + 8) = o1;
  }

  float a[8];
#pragma unroll
  for (int e = 0; e < 8; ++e) a[e] = 0.f;
#pragma unroll
  for (int i = 0; i < 16; ++i) {
    float xs = xv[i >> 2][i & 3];
    const float* wr = rw + (size_t)(d0 + i) * 8;
    f32x4 w0 = *(const f32x4*)(wr);
    f32x4 w1 = *(const f32x4*)(wr + 4);
#pragma unroll
    for (int e = 0; e < 4; ++e) a[e] = fmaf(xs, w0[e], a[e]);
#pragma unroll
    for (int e = 0; e < 4; ++e) a[4 + e] = fmaf(xs, w1[e], a[4 + e]);
  }
#pragma unroll
  for (int off = 32; off > 0; off >>= 1) {
#pragma unroll
    for (int e = 0; e < 8; ++e) a[e] += __shfl_down(a[e], off);
  }
  if (l == 0) {
#pragma unroll
    for (int e = 0; e < 8; ++e) a[e] += rb[e];
    float m = a[0];
#pragma unroll
    for (int e = 1; e < 8; ++e) m = fmaxf(m, a[e]);
    float s = 0.f;
#pragma unroll
    for (int e = 0; e < 8; ++e) { a[e] = __expf(a[e] - m); s += a[e]; }
    float inv = 1.f / s;
#pragma unroll
    for (int e = 0; e < 8; ++e) {
      float p = a[e] * inv;
      PT[(size_t)e * 2048 + t] = p;
      probs_out[t * 8 + e] = p;
      ps[g][e] = p;
    }
  }
  __syncthreads();

  f32x4 acc[4];
#pragma unroll
  for (int i = 0; i < 4; ++i) acc[i] = {0.f, 0.f, 0.f, 0.f};
#pragma unroll
  for (int e = 0; e < 8; ++e) {
    float p = ps[g][e];
#pragma unroll
    for (int i = 0; i < 4; ++i) {
      f32x4 b = *(const f32x4*)(b2 + (size_t)e * 1024 + d0 + i * 4);
#pragma unroll
      for (int c = 0; c < 4; ++c) acc[i][c] = fmaf(p, b[c], acc[i][c]);
    }
  }
#pragma unroll
  for (int i = 0; i < 4; ++i)
    *(f32x4*)(y + (size_t)t * 1024 + d0 + i * 4) = acc[i];
}

// ---------------------------------------------------------------------------
// Router only (tier D)
// ---------------------------------------------------------------------------
__global__ void router_kernel(const float* __restrict__ x,
                              const float* __restrict__ rw,
                              const float* __restrict__ rb,
                              float* __restrict__ probs_out)
{
  int gid = blockIdx.x * blockDim.x + threadIdx.x;
  int t = gid >> 6;
  int l = gid & 63;
  const float* xr = x + (size_t)t * 1024;
  float a[8];
#pragma unroll
  for (int e = 0; e < 8; ++e) a[e] = 0.f;
  for (int d = l; d < 1024; d += 64) {
    float xv = xr[d];
    f32x4 w0 = *(const f32x4*)(rw + d * 8);
    f32x4 w1 = *(const f32x4*)(rw + d * 8 + 4);
#pragma unroll
    for (int e = 0; e < 4; ++e) a[e] += xv * w0[e];
#pragma unroll
    for (int e = 0; e < 4; ++e) a[4 + e] += xv * w1[e];
  }
#pragma unroll
  for (int off = 32; off > 0; off >>= 1) {
#pragma unroll
    for (int e = 0; e < 8; ++e) a[e] += __shfl_down(a[e], off);
  }
  if (l == 0) {
#pragma unroll
    for (int e = 0; e < 8; ++e) a[e] += rb[e];
    float m = a[0];
#pragma unroll
    for (int e = 1; e < 8; ++e) m = fmaxf(m, a[e]);
    float s = 0.f;
#pragma unroll
    for (int e = 0; e < 8; ++e) { a[e] = __expf(a[e] - m); s += a[e]; }
    float inv = 1.f / s;
#pragma unroll
    for (int e = 0; e < 8; ++e) probs_out[t * 8 + e] = a[e] * inv;
  }
}

// ---------------------------------------------------------------------------
// Transpose+convert body (R6-verified): src fp32 [z][R][C] -> dst bf16
// [c][dstLd] (+ z*zOff) holding src[r][c] at [c][..+r]. 64x256 per block.
// ---------------------------------------------------------------------------
__device__ __forceinline__ void transconv_body(const float* __restrict__ src,
                                               __bf16* __restrict__ dst,
                                               int R, int C, size_t dstLd,
                                               size_t zOff)
{
  __shared__ __bf16 tile[64][257];
  size_t bs = (size_t)blockIdx.z * (size_t)R * (size_t)C;
  size_t dzo = (size_t)blockIdx.z * zOff;
  int r0 = blockIdx.x * 64, c0 = blockIdx.y * 256;
  const int l15 = (threadIdx.x & 15) * 4;
  const int rq = threadIdx.x >> 4;
#pragma unroll
  for (int i = 0; i < 4; ++i) {
    const int row = rq + 16 * i;
    const float* sr = src + bs + (size_t)(r0 + row) * C + c0 + l15;
#pragma unroll
    for (int q = 0; q < 4; ++q) {
      f32x4 v = *(const f32x4*)(sr + q * 64);
#pragma unroll
      for (int j = 0; j < 4; ++j)
        tile[row][q * 64 + l15 + j] = (__bf16)v[j];
    }
  }
  __syncthreads();
  const int cb = threadIdx.x >> 3;
  const int orr = (threadIdx.x & 7) * 8;
#pragma unroll
  for (int g = 0; g < 8; ++g) {
    const int c = cb + 32 * g;
    bf16x8 o;
#pragma unroll
    for (int j = 0; j < 8; ++j) o[j] = tile[orr + j][c];
    *(bf16x8*)(dst + (size_t)(c0 + c) * dstLd + dzo + r0 + orr) = o;
  }
}

// separate names so rocprof top-5 can localize them
__global__ void transconv1_kernel(const float* __restrict__ src,
                                  __bf16* __restrict__ dst,
                                  int R, int C, size_t dstLd, size_t zOff)
{ transconv_body(src, dst, R, C, dstLd, zOff); }

__global__ void transconv2_kernel(const float* __restrict__ src,
                                  __bf16* __restrict__ dst,
                                  int R, int C, size_t dstLd, size_t zOff)
{ transconv_body(src, dst, R, C, dstLd, zOff); }

// ---------------------------------------------------------------------------
// 256x256 MFMA mainloop, BK=64, 2 barriers per K-tile.
// 8 waves (wm=w>>2, wn=w&3), per-wave out 128x64 = 8x4 frags of 16x16x32,
// 64 MFMA / K-tile / wave in two 32-MFMA clusters.
// LDS: buf p (p=t&1) at p*65536: A-half h (128 rows x 128B) at h*16384,
// B-half h at 32768 + h*16384. Row r: LDS chunk c = global chunk c^(r&7).
// Hazard audit: A-stages (tau=t+1) hit buffer p^1 (dead since tile t-1's
// final barrier) -> safe anywhere. B-stage (tau=t+2) hits live buffer p ->
// must follow the mid-tile barrier (all waves consumed bv via MM(0,*)).
// Tile-end: vmcnt(4) (12 in flight: B(t+1),A(t+1),B(t+2) -> drains first 8)
// + barrier -> tile t+1's reads are safe. No sched_barriers: compiler
// interleaves ds_reads under MFMA clusters with progressive lgkmcnt.
// ---------------------------------------------------------------------------
__device__ __forceinline__ void mfma_loop256(
    const char* Ab, const char* Bb, size_t ldaB, size_t ldbB, int K,
    char* lds, f32x4 acc[8][4])
{
  const int tid = threadIdx.x;
  const int w = tid >> 6, l = tid & 63;
  const int wm = w >> 2, wn = w & 3;
  const int m16 = l & 15, q = l >> 4;
  const int swz = m16 & 7;
  const int aBase = wm * 16384 + m16 * 128;
  const int bBase = 32768 + (wn >> 1) * 16384 + ((wn & 1) * 64 + m16) * 128;
  const int srcCh = ((l & 7) ^ ((l >> 3) & 7)) << 4;
  const size_t gA0 = (size_t)(w * 16 + (l >> 3)) * ldaB + srcCh;
  const size_t gB0 = (size_t)(w * 16 + (l >> 3)) * ldbB + srcCh;
  const int dstW = w * 2048;
  const int NT = K >> 6;

  bf16x8 af[4][2], bv[4][2];

#define STG_A(h, tau)                                                          \
  {                                                                            \
    char* d = lds + (((tau) & 1) * 65536) + (h) * 16384 + dstW;                \
    const char* g = Ab + gA0 + (size_t)((h) * 128) * ldaB + (size_t)(tau) * 128;\
    GLL16(g, d);                                                               \
    GLL16(g + 8 * ldaB, d + 1024);                                             \
  }
#define STG_B(h, tau)                                                          \
  {                                                                            \
    char* d = lds + (((tau) & 1) * 65536) + 32768 + (h) * 16384 + dstW;        \
    const char* g = Bb + gB0 + (size_t)((h) * 128) * ldbB + (size_t)(tau) * 128;\
    GLL16(g, d);                                                               \
    GLL16(g + 8 * ldbB, d + 1024);                                             \
  }
#define RD_A(lo, p)                                                            \
  _Pragma("unroll") for (int mi = 0; mi < 4; ++mi)                             \
  _Pragma("unroll") for (int ks = 0; ks < 2; ++ks)                             \
    af[mi][ks] = *(const bf16x8*)(lds + (p) * 65536 + aBase +                  \
        ((lo) * 4 + mi) * 2048 + (((ks * 4 + q) ^ swz) << 4));
#define RD_B(no, p)                                                            \
  _Pragma("unroll") for (int nj = 0; nj < 2; ++nj)                             \
  _Pragma("unroll") for (int ks = 0; ks < 2; ++ks)                             \
    bv[(no) * 2 + nj][ks] = *(const bf16x8*)(lds + (p) * 65536 + bBase +       \
        ((no) * 2 + nj) * 2048 + (((ks * 4 + q) ^ swz) << 4));
#define MM(lo, no)                                                             \
  _Pragma("unroll") for (int mi = 0; mi < 4; ++mi)                             \
  _Pragma("unroll") for (int nj = 0; nj < 2; ++nj)                             \
  _Pragma("unroll") for (int ks = 0; ks < 2; ++ks)                             \
    acc[(lo) * 4 + mi][(no) * 2 + nj] =                                        \
        __builtin_amdgcn_mfma_f32_16x16x32_bf16(                               \
            af[mi][ks], bv[(no) * 2 + nj][ks],                                 \
            acc[(lo) * 4 + mi][(no) * 2 + nj], 0, 0, 0);
#define MMP(lo)                                                                \
  __builtin_amdgcn_s_setprio(1);                                               \
  MM(lo, 0); MM(lo, 1);                                                        \
  __builtin_amdgcn_s_setprio(0);
#define BARR __builtin_amdgcn_s_barrier()
#define VMW(n) asm volatile("s_waitcnt vmcnt(" #n ")" ::: "memory")

  // Prologue: tile 0 fully + B halves of tile 1. vmcnt(4) leaves B(1)
  // outstanding; A(0),B(0) landed.
  STG_A(0, 0); STG_A(1, 0); STG_B(0, 0); STG_B(1, 0);
  STG_B(0, 1); STG_B(1, 1);
  VMW(4);
  BARR;

  int t = 0;
  for (; t < NT - 2; ++t) {
    const int p = t & 1;
    RD_B(0, p); RD_B(1, p); RD_A(0, p);
    STG_A(0, t + 1); STG_A(1, t + 1);
    MMP(0);                    // consumes all bv + af(0); LDS reads drain
    BARR;                      // under MFMA via progressive lgkmcnt
    STG_B(0, t + 2); STG_B(1, t + 2);
    RD_A(1, p);
    MMP(1);
    VMW(4);
    BARR;
  }
  {  // t = NT-2: stage only A(NT-1); full drain at end
    const int p = t & 1;
    RD_B(0, p); RD_B(1, p); RD_A(0, p);
    STG_A(0, t + 1); STG_A(1, t + 1);
    MMP(0);
    BARR;
    RD_A(1, p);
    MMP(1);
    VMW(0);
    BARR;
    ++t;
  }
  {  // t = NT-1: all resident, no stages -> no barriers
    const int p = t & 1;
    RD_B(0, p); RD_B(1, p); RD_A(0, p);
    MMP(0);
    RD_A(1, p);
    MMP(1);
  }
#undef STG_A
#undef STG_B
#undef RD_A
#undef RD_B
#undef MM
#undef MMP
#undef BARR
#undef VMW
}

// bijective XCD-chunked block swizzle (nwg % 8 == 0 for all our grids)
__device__ __forceinline__ int xcd_swz(int id, int nwg) {
  return ((nwg & 7) == 0) ? ((id & 7) * (nwg >> 3) + (id >> 3)) : id;
}

// ---------------------------------------------------------------------------
// GEMM1: Hs[t, zcol+h] = PT[e,t] * gelu(Xb @ W1T_e^T + b1_e)   (bf16 store)
// grid (8, N/256, Z), 512 threads
// ---------------------------------------------------------------------------
__global__ __launch_bounds__(512, 2) void gemm1_kernel(
    const __bf16* __restrict__ X, const __bf16* __restrict__ W1T,
    const float* __restrict__ b1, const float* __restrict__ PT,
    __bf16* __restrict__ Hs, int hs_ld, int e_off, size_t b_zstride)
{
  __shared__ __align__(16) char lds[131072];
  const int nwg = gridDim.x * gridDim.y * gridDim.z;
  const int id = blockIdx.x + gridDim.x * (blockIdx.y + gridDim.y * blockIdx.z);
  const int wg = xcd_swz(id, nwg);
  const int bm = wg & 7;
  const int bn = (wg >> 3) % gridDim.y;
  const int z = wg / (gridDim.y << 3);
  const int e = z + e_off;

  f32x4 acc[8][4];
  const f32x4 z4 = {0.f, 0.f, 0.f, 0.f};
#pragma unroll
  for (int i = 0; i < 8; ++i)
#pragma unroll
    for (int j = 0; j < 4; ++j) acc[i][j] = z4;

  const char* A = (const char*)(X + (size_t)bm * 256 * 1024);
  const char* B = (const char*)(W1T + (size_t)z * b_zstride +
                                (size_t)bn * 256 * 1024);
  mfma_loop256(A, B, 2048, 2048, 1024, lds, acc);

  const int tid = threadIdx.x, w = tid >> 6, l = tid & 63;
  const int wm = w >> 2, wn = w & 3, q = l >> 4, m16 = l & 15;
  const int row0 = bm * 256 + wm * 128 + q * 4;
  const int colE = bn * 256 + wn * 64 + m16;
  const int zcol = (hs_ld == 4096) ? 0 : z * 4096;
  float b1v[4];
#pragma unroll
  for (int nj = 0; nj < 4; ++nj)
    b1v[nj] = b1[(size_t)e * 4096 + colE + nj * 16];
#pragma unroll
  for (int mi = 0; mi < 8; ++mi) {
    float pv[4];
#pragma unroll
    for (int r = 0; r < 4; ++r)
      pv[r] = PT[(size_t)e * 2048 + row0 + mi * 16 + r];
#pragma unroll
    for (int nj = 0; nj < 4; ++nj)
#pragma unroll
      for (int r = 0; r < 4; ++r) {
        float h = acc[mi][nj][r] + b1v[nj];
        float o = gelu_f(h) * pv[r];
        Hs[(size_t)(row0 + mi * 16 + r) * hs_ld + zcol + colE + nj * 16] =
            (__bf16)o;
      }
  }
}

// ---------------------------------------------------------------------------
// GEMM2: y[t,d] += Hs_chunk @ W2T_chunk^T (split-K via z, fp32 atomics into
// the bias-pre-initialized output). grid (8, 4, Z), 512 threads.
// ---------------------------------------------------------------------------
__global__ __launch_bounds__(512, 2) void gemm2_kernel(
    const __bf16* __restrict__ Hs, const __bf16* __restrict__ W2T,
    float* __restrict__ y, int lda, int ldb, int kz, int Kb)
{
  __shared__ __align__(16) char lds[131072];
  const int nwg = gridDim.x * gridDim.y * gridDim.z;
  const int id = blockIdx.x + gridDim.x * (blockIdx.y + gridDim.y * blockIdx.z);
  const int wg = xcd_swz(id, nwg);
  const int bm = wg & 7;
  const int bn = (wg >> 3) % gridDim.y;
  const int z = wg / (gridDim.y << 3);

  f32x4 acc[8][4];
  const f32x4 z4 = {0.f, 0.f, 0.f, 0.f};
#pragma unroll
  for (int i = 0; i < 8; ++i)
#pragma unroll
    for (int j = 0; j < 4; ++j) acc[i][j] = z4;

  const char* A = (const char*)(Hs + (size_t)bm * 256 * lda + (size_t)z * kz);
  const char* B = (const char*)(W2T + (size_t)bn * 256 * ldb + (size_t)z * kz);
  mfma_loop256(A, B, (size_t)lda * 2, (size_t)ldb * 2, Kb, lds, acc);

  const int tid = threadIdx.x, w = tid >> 6, l = tid & 63;
  const int wm = w >> 2, wn = w & 3, q = l >> 4, m16 = l & 15;
  const int row0 = bm * 256 + wm * 128 + q * 4;
  const int col0 = bn * 256 + wn * 64 + m16;
#pragma unroll
  for (int mi = 0; mi < 8; ++mi)
#pragma unroll
    for (int nj = 0; nj < 4; ++nj)
#pragma unroll
      for (int r = 0; r < 4; ++r)
        unsafeAtomicAdd(
            y + (size_t)(row0 + mi * 16 + r) * 1024 + col0 + nj * 16,
            acc[mi][nj][r]);
}

// ---------------------------------------------------------------------------
// Tier D: zero-workspace fused VALU fallback (fp32)
// ---------------------------------------------------------------------------
__global__ __launch_bounds__(256) void fused_naive_kernel(
    const float* __restrict__ x, const float* __restrict__ w1,
    const float* __restrict__ b1, const float* __restrict__ w2,
    const float* __restrict__ b2, const float* __restrict__ probs,
    float* __restrict__ y)
{
  __shared__ float xs[8][1024];
  __shared__ float gs[8][64];
  __shared__ float ps[8];
  const int tid = threadIdx.x;
  const int t0 = blockIdx.x * 8;
  const size_t DH = (size_t)1024 * 4096;
  const int tt = tid >> 5;
  const int d0 = (tid & 31) * 32;
  float acc[32];
#pragma unroll
  for (int i = 0; i < 32; ++i) acc[i] = 0.f;
  {
    const f32x4* xsrc = (const f32x4*)(x + (size_t)t0 * 1024);
    f32x4* xdst = (f32x4*)&xs[0][0];
    for (int i = tid; i < 2048; i += 256) xdst[i] = xsrc[i];
  }
  const int wv = tid >> 6;
  const int hl = tid & 63;
  for (int e = 0; e < 8; ++e) {
    if (tid < 8) ps[tid] = probs[(size_t)(t0 + tid) * 8 + e];
    __syncthreads();
    for (int hc = 0; hc < 4096; hc += 64) {
      float a0 = 0.f, a1 = 0.f;
      const float* w1p = w1 + (size_t)e * DH + hc + hl;
      for (int d = 0; d < 1024; ++d) {
        float wvv = w1p[(size_t)d * 4096];
        a0 += xs[wv * 2 + 0][d] * wvv;
        a1 += xs[wv * 2 + 1][d] * wvv;
      }
      __syncthreads();
      gs[wv * 2 + 0][hl] =
          ps[wv * 2 + 0] * gelu_f(a0 + b1[(size_t)e * 4096 + hc + hl]);
      gs[wv * 2 + 1][hl] =
          ps[wv * 2 + 1] * gelu_f(a1 + b1[(size_t)e * 4096 + hc + hl]);
      __syncthreads();
      const float* w2p = w2 + (size_t)e * DH + (size_t)hc * 1024 + d0;
      for (int hh = 0; hh < 64; ++hh) {
        float g = gs[tt][hh];
#pragma unroll
        for (int jb = 0; jb < 8; ++jb) {
          f32x4 w4 = *(const f32x4*)(w2p + (size_t)hh * 1024 + jb * 4);
#pragma unroll
          for (int j2 = 0; j2 < 4; ++j2) acc[jb * 4 + j2] += g * w4[j2];
        }
      }
    }
#pragma unroll
    for (int j = 0; j < 32; ++j)
      acc[j] += ps[tt] * b2[(size_t)e * 1024 + d0 + j];
    __syncthreads();
  }
  float* yp = y + (size_t)(t0 + tt) * 1024 + d0;
#pragma unroll
  for (int jb = 0; jb < 8; ++jb) {
    f32x4 o = {acc[jb * 4], acc[jb * 4 + 1], acc[jb * 4 + 2], acc[jb * 4 + 3]};
    *(f32x4*)(yp + jb * 4) = o;
  }
}

// ---------------------------------------------------------------------------
extern "C" void kernel_launch(void* const* d_in, const int* in_sizes, int n_in,
                              void* d_out, int out_size, void* d_ws,
                              size_t ws_size, hipStream_t stream)
{
  const float* x  = (const float*)d_in[0];  // [2048,1024]
  const float* rw = (const float*)d_in[1];  // [1024,8]
  const float* rb = (const float*)d_in[2];  // [8]
  const float* w1 = (const float*)d_in[3];  // [8,1024,4096]
  const float* b1 = (const float*)d_in[4];  // [8,4096]
  const float* w2 = (const float*)d_in[5];  // [8,4096,1024]
  const float* b2 = (const float*)d_in[6];  // [8,1024]
  float* y = (float*)d_out;                   // [2048,1024]
  float* probs_out = y + (size_t)2048 * 1024; // [2048,8]

  const size_t DH = (size_t)1024 * 4096;
  const size_t BASE = (64 << 10) + (size_t)2048 * 1024 * 2;      // PT | xb
  const size_t TA = BASE + 8 * DH * 2 + (size_t)2048 * 32768 * 2;  // ~196.2MB
  const size_t TB = BASE + DH * 2 + (size_t)2048 * 4096 * 2;       // ~28.2MB

  char* ws = (char*)d_ws;
  float* PT = (float*)ws;
  __bf16* xb = (__bf16*)(ws + (64 << 10));
  __bf16* WT = (__bf16*)(ws + BASE);

  if (ws_size >= TA) {
    pre_kernel<<<512, 256, 0, stream>>>(x, rw, rb, b2, PT, probs_out, xb, y);
    __bf16* Hs = WT + 8 * DH;       // [2048][32768] bf16
    transconv1_kernel<<<dim3(16, 16, 8), 256, 0, stream>>>(
        w1, WT, 1024, 4096, 1024, DH);
    gemm1_kernel<<<dim3(8, 16, 8), 512, 0, stream>>>(xb, WT, b1, PT, Hs,
                                                     32768, 0, DH);
    transconv2_kernel<<<dim3(64, 4, 8), 256, 0, stream>>>(
        w2, WT, 4096, 1024, 32768, 4096);
    gemm2_kernel<<<dim3(8, 4, 8), 512, 0, stream>>>(Hs, WT, y, 32768,
                                                    32768, 4096, 4096);
  } else if (ws_size >= TB) {
    pre_kernel<<<512, 256, 0, stream>>>(x, rw, rb, b2, PT, probs_out, xb, y);
    __bf16* HsE = WT + DH;          // 16 MB
    for (int e = 0; e < 8; ++e) {
      transconv1_kernel<<<dim3(16, 16, 1), 256, 0, stream>>>(
          w1 + (size_t)e * DH, WT, 1024, 4096, 1024, 0);
      gemm1_kernel<<<dim3(8, 16, 1), 512, 0, stream>>>(xb, WT, b1, PT, HsE,
                                                       4096, e, 0);
      transconv2_kernel<<<dim3(64, 4, 1), 256, 0, stream>>>(
          w2 + (size_t)e * DH, WT, 4096, 1024, 4096, 0);
      gemm2_kernel<<<dim3(8, 4, 4), 512, 0, stream>>>(HsE, WT, y, 4096,
                                                      4096, 1024, 1024);
    }
  } else {
    router_kernel<<<512, 256, 0, stream>>>(x, rw, rb, probs_out);
    fused_naive_kernel<<<256, 256, 0, stream>>>(x, w1, b1, w2, b2, probs_out,
                                                y);
  }
}